// Round 1
// baseline (101.738 us; speedup 1.0000x reference)
//
#include <hip/hip_runtime.h>

// mrnLoss: out = sum((w_preds - w_stars)^2) + N - sum_n( y_n * <feats_n, w_preds[seg_n]> )
// C=1000, D=512, N=200000. Memory-bound: feats = 409.6 MB read once.

#define BLOCK 256
#define GRID  2048

__global__ void init_out(float* out, float n_const) {
    out[0] = n_const;
}

__global__ __launch_bounds__(BLOCK) void mrn_loss_kernel(
    const float* __restrict__ wp,   // (C, D) = (1000, 512)
    const float* __restrict__ wst,  // (C, D)
    const float* __restrict__ feats,// (N, D)
    const float* __restrict__ ys,   // (N,)
    const int*   __restrict__ seg,  // (N,)
    float* __restrict__ out,
    int N)
{
    const int tid      = blockIdx.x * BLOCK + threadIdx.x;
    const int nthreads = gridDim.x * BLOCK;

    float acc = 0.0f;

    // ---- Part 1: reg_loss = sum((wp - wst)^2) over C*D = 512000 floats = 128000 float4
    {
        const int REG4 = (1000 * 512) / 4;
        const float4* wp4 = (const float4*)wp;
        const float4* ws4 = (const float4*)wst;
        for (int i = tid; i < REG4; i += nthreads) {
            float4 a = wp4[i];
            float4 b = ws4[i];
            float dx = a.x - b.x, dy = a.y - b.y, dz = a.z - b.z, dw = a.w - b.w;
            acc += dx * dx + dy * dy + dz * dz + dw * dw;
        }
    }

    // ---- Part 2: -sum_n y_n * <feats_n, wp[seg_n]> ; one wave (64 lanes) per sample.
    // Row = 512 floats = 128 float4; lane reads float4 at [lane] and [lane+64].
    {
        const int lane   = threadIdx.x & 63;
        const int wave   = tid >> 6;
        const int nwaves = nthreads >> 6;
        const float4* f4 = (const float4*)feats;

        for (int n = wave; n < N; n += nwaves) {
            const int   c = seg[n];
            const float y = ys[n];
            const float4* fr = f4 + (size_t)n * 128;
            const float4* wr = (const float4*)(wp + (size_t)c * 512);
            float4 f0 = fr[lane];
            float4 f1 = fr[lane + 64];
            float4 w0 = wr[lane];
            float4 w1 = wr[lane + 64];
            float d = f0.x * w0.x + f0.y * w0.y + f0.z * w0.z + f0.w * w0.w
                    + f1.x * w1.x + f1.y * w1.y + f1.z * w1.z + f1.w * w1.w;
            acc -= y * d;
        }
    }

    // ---- Reduce: shuffle within wave, LDS across waves, one atomic per block.
    for (int off = 32; off > 0; off >>= 1)
        acc += __shfl_down(acc, off, 64);

    __shared__ float sacc[BLOCK / 64];
    const int lane = threadIdx.x & 63;
    const int wid  = threadIdx.x >> 6;
    if (lane == 0) sacc[wid] = acc;
    __syncthreads();

    if (threadIdx.x == 0) {
        float b = sacc[0] + sacc[1] + sacc[2] + sacc[3];
        atomicAdd(out, b);
    }
}

extern "C" void kernel_launch(void* const* d_in, const int* in_sizes, int n_in,
                              void* d_out, int out_size, void* d_ws, size_t ws_size,
                              hipStream_t stream) {
    const float* wp    = (const float*)d_in[0];
    const float* wst   = (const float*)d_in[1];
    const float* feats = (const float*)d_in[2];
    const float* ys    = (const float*)d_in[3];
    const int*   seg   = (const int*)d_in[4];
    float* out = (float*)d_out;

    const int N = in_sizes[3];   // 200000 samples

    // perf_loss contributes +1 per sample: fold into init constant.
    init_out<<<1, 1, 0, stream>>>(out, (float)N);
    mrn_loss_kernel<<<GRID, BLOCK, 0, stream>>>(wp, wst, feats, ys, seg, out, N);
}

// Round 2
// 82.510 us; speedup vs baseline: 1.2330x; 1.2330x over previous
//
#include <hip/hip_runtime.h>

// mrnLoss: out = sum((w_preds - w_stars)^2) + N - sum_n( y_n * <feats_n, w_preds[seg_n]> )
// C=1000, D=512, N=200000. Memory-bound: feats = 409.6 MB read once -> ~66us floor @6.3TB/s.
//
// R1 changes vs R0 (101.7us):
//  - contiguous per-wave sample chunks (streaming feats reads, DRAM page locality)
//  - batched coalesced preload of seg/ys per chunk, __shfl broadcast (kills the
//    per-sample seg-load -> wp-gather dependent chain)
//  - 2x unroll for MLP (8 float4 loads in flight)
//  - non-temporal feats loads (don't thrash wp's 2MB out of 4MB/XCD L2)

#define BLOCK 256
#define GRID  2048

typedef float vf4 __attribute__((ext_vector_type(4)));

__global__ void init_out(float* out, float n_const) {
    out[0] = n_const;
}

__global__ __launch_bounds__(BLOCK) void mrn_loss_kernel(
    const float* __restrict__ wp,   // (C, D) = (1000, 512)
    const float* __restrict__ wst,  // (C, D)
    const float* __restrict__ feats,// (N, D)
    const float* __restrict__ ys,   // (N,)
    const int*   __restrict__ seg,  // (N,)
    float* __restrict__ out,
    int N)
{
    const int tid      = blockIdx.x * BLOCK + threadIdx.x;
    const int nthreads = gridDim.x * BLOCK;

    float acc = 0.0f;

    // ---- Part 1: reg_loss = sum((wp - wst)^2) over C*D = 512000 floats
    {
        const int REG4 = (1000 * 512) / 4;
        const vf4* wp4 = (const vf4*)wp;
        const vf4* ws4 = (const vf4*)wst;
        for (int i = tid; i < REG4; i += nthreads) {
            vf4 a = wp4[i];
            vf4 b = ws4[i];
            vf4 d = a - b;
            acc += d.x * d.x + d.y * d.y + d.z * d.z + d.w * d.w;
        }
    }

    // ---- Part 2: -sum_n y_n * <feats_n, wp[seg_n]>
    // One wave per CHUNK of consecutive samples. Lane reads float4 [lane] and
    // [lane+64] of each 512-float row.
    {
        const int lane   = threadIdx.x & 63;
        const int wave   = tid >> 6;
        const int nwaves = nthreads >> 6;
        const int chunk  = (N + nwaves - 1) / nwaves;   // 25 for N=200000, 8192 waves
        const int base   = wave * chunk;
        const int cnt    = (base < N) ? min(chunk, N - base) : 0;
        const vf4* f4 = (const vf4*)feats;

        for (int jb = 0; jb < cnt; jb += 64) {
            const int bcnt = min(64, cnt - jb);
            const int sidx = base + jb;

            // Coalesced preload of this batch's seg/ys (one transaction each).
            int   myseg = 0;
            float myy   = 0.0f;
            if (lane < bcnt) {
                myseg = seg[sidx + lane];
                myy   = ys[sidx + lane];
            }

            int j = 0;
            for (; j + 1 < bcnt; j += 2) {
                const int   c0 = __shfl(myseg, j,     64);
                const int   c1 = __shfl(myseg, j + 1, 64);
                const float y0 = __shfl(myy,   j,     64);
                const float y1 = __shfl(myy,   j + 1, 64);

                const vf4* fr0 = f4 + (size_t)(sidx + j) * 128;
                const vf4* fr1 = fr0 + 128;
                const vf4* wr0 = (const vf4*)(wp + (size_t)c0 * 512);
                const vf4* wr1 = (const vf4*)(wp + (size_t)c1 * 512);

                // feats: streamed once -> non-temporal (keep wp hot in L2)
                vf4 a0 = __builtin_nontemporal_load(fr0 + lane);
                vf4 a1 = __builtin_nontemporal_load(fr0 + lane + 64);
                vf4 b0 = __builtin_nontemporal_load(fr1 + lane);
                vf4 b1 = __builtin_nontemporal_load(fr1 + lane + 64);
                // wp: hot working set (2MB), normal cached loads
                vf4 u0 = wr0[lane];
                vf4 u1 = wr0[lane + 64];
                vf4 v0 = wr1[lane];
                vf4 v1 = wr1[lane + 64];

                float d0 = a0.x * u0.x + a0.y * u0.y + a0.z * u0.z + a0.w * u0.w
                         + a1.x * u1.x + a1.y * u1.y + a1.z * u1.z + a1.w * u1.w;
                float d1 = b0.x * v0.x + b0.y * v0.y + b0.z * v0.z + b0.w * v0.w
                         + b1.x * v1.x + b1.y * v1.y + b1.z * v1.z + b1.w * v1.w;
                acc -= y0 * d0;
                acc -= y1 * d1;
            }
            if (j < bcnt) {
                const int   c0 = __shfl(myseg, j, 64);
                const float y0 = __shfl(myy,   j, 64);
                const vf4* fr0 = f4 + (size_t)(sidx + j) * 128;
                const vf4* wr0 = (const vf4*)(wp + (size_t)c0 * 512);
                vf4 a0 = __builtin_nontemporal_load(fr0 + lane);
                vf4 a1 = __builtin_nontemporal_load(fr0 + lane + 64);
                vf4 u0 = wr0[lane];
                vf4 u1 = wr0[lane + 64];
                float d0 = a0.x * u0.x + a0.y * u0.y + a0.z * u0.z + a0.w * u0.w
                         + a1.x * u1.x + a1.y * u1.y + a1.z * u1.z + a1.w * u1.w;
                acc -= y0 * d0;
            }
        }
    }

    // ---- Reduce: shuffle within wave, LDS across waves, one atomic per block.
    for (int off = 32; off > 0; off >>= 1)
        acc += __shfl_down(acc, off, 64);

    __shared__ float sacc[BLOCK / 64];
    const int lane = threadIdx.x & 63;
    const int wid  = threadIdx.x >> 6;
    if (lane == 0) sacc[wid] = acc;
    __syncthreads();

    if (threadIdx.x == 0) {
        float b = sacc[0] + sacc[1] + sacc[2] + sacc[3];
        atomicAdd(out, b);
    }
}

extern "C" void kernel_launch(void* const* d_in, const int* in_sizes, int n_in,
                              void* d_out, int out_size, void* d_ws, size_t ws_size,
                              hipStream_t stream) {
    const float* wp    = (const float*)d_in[0];
    const float* wst   = (const float*)d_in[1];
    const float* feats = (const float*)d_in[2];
    const float* ys    = (const float*)d_in[3];
    const int*   seg   = (const int*)d_in[4];
    float* out = (float*)d_out;

    const int N = in_sizes[3];   // 200000 samples

    // perf_loss contributes +1 per sample: fold into init constant.
    init_out<<<1, 1, 0, stream>>>(out, (float)N);
    mrn_loss_kernel<<<GRID, BLOCK, 0, stream>>>(wp, wst, feats, ys, seg, out, N);
}

// Round 3
// 81.951 us; speedup vs baseline: 1.2414x; 1.0068x over previous
//
#include <hip/hip_runtime.h>

// mrnLoss: out = sum((w_preds - w_stars)^2) + N - sum_n( y_n * <feats_n, w_preds[seg_n]> )
// C=1000, D=512, N=200000. Memory-bound: feats = 409.6 MB read once -> ~62us floor @6.7TB/s.
//
// R2 changes vs R1 (82.5us):
//  - kill the DS-pipe dependent chain: __shfl(myseg,j) (ds_bpermute, lgkmcnt)
//    -> __builtin_amdgcn_readlane with compile-time j (VALU->SGPR, scalar wp base)
//  - readfirstlane(wave) so feats addresses are SGPR-base + lane*16 voffset
//  - fixed CHUNK=25 samples/wave, #pragma unroll 5 (deep load pipelining)
//  - two alternating accumulators (shorter FMA chain)

#define BLOCK 256
#define GRID  2048
#define CHUNK 25

typedef float vf4 __attribute__((ext_vector_type(4)));

__global__ void init_out(float* out, float n_const) {
    out[0] = n_const;
}

__device__ __forceinline__ float dot8(vf4 a0, vf4 a1, vf4 u0, vf4 u1) {
    return a0.x * u0.x + a0.y * u0.y + a0.z * u0.z + a0.w * u0.w
         + a1.x * u1.x + a1.y * u1.y + a1.z * u1.z + a1.w * u1.w;
}

__global__ __launch_bounds__(BLOCK) void mrn_loss_kernel(
    const float* __restrict__ wp,   // (C, D) = (1000, 512)
    const float* __restrict__ wst,  // (C, D)
    const float* __restrict__ feats,// (N, D)
    const float* __restrict__ ys,   // (N,)
    const int*   __restrict__ seg,  // (N,)
    float* __restrict__ out,
    int N)
{
    const int tid      = blockIdx.x * BLOCK + threadIdx.x;
    const int nthreads = gridDim.x * BLOCK;

    float acc_a = 0.0f;
    float acc_b = 0.0f;

    // ---- Part 1: reg_loss = sum((wp - wst)^2) over C*D = 512000 floats
    {
        const int REG4 = (1000 * 512) / 4;
        const vf4* wp4 = (const vf4*)wp;
        const vf4* ws4 = (const vf4*)wst;
        for (int i = tid; i < REG4; i += nthreads) {
            vf4 a = wp4[i];
            vf4 b = ws4[i];
            vf4 d = a - b;
            acc_a += d.x * d.x + d.y * d.y + d.z * d.z + d.w * d.w;
        }
    }

    // ---- Part 2: -sum_n y_n * <feats_n, wp[seg_n]>
    // One wave per CHUNK=25 consecutive samples. Lane reads float4 [lane] and
    // [lane+64] of each 512-float row.
    {
        const int lane = threadIdx.x & 63;
        // Force wave id into an SGPR so all row bases are scalar addresses.
        const int wave = __builtin_amdgcn_readfirstlane(tid >> 6);
        const int base = wave * CHUNK;

        if (base < N) {
            const int cnt = min(CHUNK, N - base);

            // Coalesced preload of this chunk's seg/ys (one transaction each).
            int   myseg = 0;
            float myy   = 0.0f;
            if (lane < cnt) {
                myseg = seg[base + lane];
                myy   = ys[base + lane];
            }

            const vf4* f4 = (const vf4*)feats + (size_t)base * 128;

            if (cnt == CHUNK) {
                // Full chunk: compile-time readlane -> SGPR class index, no DS ops.
                #pragma unroll 5
                for (int j = 0; j < CHUNK; ++j) {
                    const int   c = __builtin_amdgcn_readlane(myseg, j);
                    const float y = __int_as_float(
                        __builtin_amdgcn_readlane(__float_as_int(myy), j));

                    const vf4* fr = f4 + (size_t)j * 128;
                    const vf4* wr = (const vf4*)(wp + (size_t)c * 512);

                    vf4 a0 = __builtin_nontemporal_load(fr + lane);
                    vf4 a1 = __builtin_nontemporal_load(fr + lane + 64);
                    vf4 u0 = wr[lane];
                    vf4 u1 = wr[lane + 64];

                    const float d = dot8(a0, a1, u0, u1);
                    if (j & 1) acc_b -= y * d;
                    else       acc_a -= y * d;
                }
            } else {
                // Tail wave (only if N % CHUNK != 0): dynamic path via shfl.
                for (int j = 0; j < cnt; ++j) {
                    const int   c = __shfl(myseg, j, 64);
                    const float y = __shfl(myy,   j, 64);
                    const vf4* fr = f4 + (size_t)j * 128;
                    const vf4* wr = (const vf4*)(wp + (size_t)c * 512);
                    vf4 a0 = __builtin_nontemporal_load(fr + lane);
                    vf4 a1 = __builtin_nontemporal_load(fr + lane + 64);
                    vf4 u0 = wr[lane];
                    vf4 u1 = wr[lane + 64];
                    acc_a -= y * dot8(a0, a1, u0, u1);
                }
            }
        }
    }

    // ---- Reduce: shuffle within wave, LDS across waves, one atomic per block.
    float acc = acc_a + acc_b;
    for (int off = 32; off > 0; off >>= 1)
        acc += __shfl_down(acc, off, 64);

    __shared__ float sacc[BLOCK / 64];
    const int lane = threadIdx.x & 63;
    const int wid  = threadIdx.x >> 6;
    if (lane == 0) sacc[wid] = acc;
    __syncthreads();

    if (threadIdx.x == 0) {
        float b = sacc[0] + sacc[1] + sacc[2] + sacc[3];
        atomicAdd(out, b);
    }
}

extern "C" void kernel_launch(void* const* d_in, const int* in_sizes, int n_in,
                              void* d_out, int out_size, void* d_ws, size_t ws_size,
                              hipStream_t stream) {
    const float* wp    = (const float*)d_in[0];
    const float* wst   = (const float*)d_in[1];
    const float* feats = (const float*)d_in[2];
    const float* ys    = (const float*)d_in[3];
    const int*   seg   = (const int*)d_in[4];
    float* out = (float*)d_out;

    const int N = in_sizes[3];   // 200000 samples

    // perf_loss contributes +1 per sample: fold into init constant.
    init_out<<<1, 1, 0, stream>>>(out, (float)N);
    mrn_loss_kernel<<<GRID, BLOCK, 0, stream>>>(wp, wst, feats, ys, seg, out, N);
}

// Round 4
// 78.718 us; speedup vs baseline: 1.2924x; 1.0411x over previous
//
#include <hip/hip_runtime.h>

// mrnLoss: out = sum((w_preds - w_stars)^2) + N - sum_n( y_n * <feats_n, w_preds[seg_n]> )
// C=1000, D=512, N=200000. Memory-bound: ~430 MB total read -> ~66us floor @6.5TB/s.
//
// R4 changes vs R3 (82.0us):
//  - GRID 2048->1024, CHUNK 25->49, __launch_bounds__(256,4): exactly-resident
//    (4 blocks/CU), single dispatch batch, 98KB contiguous stream per wave,
//    half the chunk-start preload bubbles
//  - unroll 3 (sufficient MLP; keeps VGPR <= 128 for 4 waves/SIMD)
//  - per-block partials -> d_ws + final tiny reduce kernel: removes the init
//    dispatch AND the 2048 same-address cross-XCD atomic drain

#define BLOCK 256
#define GRID  1024
#define CHUNK 49
#define NWAVES (GRID * (BLOCK / 64))   // 4096 waves

typedef float vf4 __attribute__((ext_vector_type(4)));

__global__ void init_out(float* out, float n_const) { out[0] = n_const; }

__global__ void final_reduce(const float* __restrict__ part, float* __restrict__ out,
                             float n_const) {
    // 256 threads reduce GRID=1024 partials.
    float a = 0.0f;
    for (int i = threadIdx.x; i < GRID; i += 256) a += part[i];
    for (int off = 32; off > 0; off >>= 1) a += __shfl_down(a, off, 64);
    __shared__ float s[4];
    if ((threadIdx.x & 63) == 0) s[threadIdx.x >> 6] = a;
    __syncthreads();
    if (threadIdx.x == 0) out[0] = n_const + s[0] + s[1] + s[2] + s[3];
}

__device__ __forceinline__ float dot8(vf4 a0, vf4 a1, vf4 u0, vf4 u1) {
    return a0.x * u0.x + a0.y * u0.y + a0.z * u0.z + a0.w * u0.w
         + a1.x * u1.x + a1.y * u1.y + a1.z * u1.z + a1.w * u1.w;
}

__global__ __launch_bounds__(BLOCK, 4) void mrn_loss_kernel(
    const float* __restrict__ wp,   // (C, D) = (1000, 512)
    const float* __restrict__ wst,  // (C, D)
    const float* __restrict__ feats,// (N, D)
    const float* __restrict__ ys,   // (N,)
    const int*   __restrict__ seg,  // (N,)
    float* __restrict__ blockout,   // per-block partials (d_ws) or null
    float* __restrict__ out,        // atomic fallback target
    int N)
{
    const int tid      = blockIdx.x * BLOCK + threadIdx.x;
    const int nthreads = GRID * BLOCK;

    float acc_a = 0.0f;
    float acc_b = 0.0f;

    // ---- Part 1: reg_loss = sum((wp - wst)^2); also warms wp into every XCD L2.
    {
        const int REG4 = (1000 * 512) / 4;
        const vf4* wp4 = (const vf4*)wp;
        const vf4* ws4 = (const vf4*)wst;
        for (int i = tid; i < REG4; i += nthreads) {
            vf4 a = wp4[i];
            vf4 b = ws4[i];
            vf4 d = a - b;
            acc_a += d.x * d.x + d.y * d.y + d.z * d.z + d.w * d.w;
        }
    }

    // ---- Part 2: -sum_n y_n * <feats_n, wp[seg_n]>
    // One wave per CHUNK=49 consecutive samples (98KB contiguous feats stream).
    {
        const int lane = threadIdx.x & 63;
        const int wave = __builtin_amdgcn_readfirstlane(tid >> 6);

        for (int base = wave * CHUNK; base < N; base += NWAVES * CHUNK) {
            const int cnt = min(CHUNK, N - base);

            // Coalesced preload of this chunk's seg/ys (one transaction each).
            int   myseg = 0;
            float myy   = 0.0f;
            if (lane < cnt) {
                myseg = seg[base + lane];
                myy   = ys[base + lane];
            }

            const vf4* f4 = (const vf4*)feats + (size_t)base * 128;

            if (cnt == CHUNK) {
                #pragma unroll 3
                for (int j = 0; j < CHUNK; ++j) {
                    const int   c = __builtin_amdgcn_readlane(myseg, j);
                    const float y = __int_as_float(
                        __builtin_amdgcn_readlane(__float_as_int(myy), j));

                    const vf4* fr = f4 + (size_t)j * 128;
                    const vf4* wr = (const vf4*)(wp + (size_t)c * 512);

                    vf4 a0 = __builtin_nontemporal_load(fr + lane);
                    vf4 a1 = __builtin_nontemporal_load(fr + lane + 64);
                    vf4 u0 = wr[lane];
                    vf4 u1 = wr[lane + 64];

                    const float d = dot8(a0, a1, u0, u1);
                    if (j & 1) acc_b -= y * d;
                    else       acc_a -= y * d;
                }
            } else {
                for (int j = 0; j < cnt; ++j) {
                    const int   c = __builtin_amdgcn_readlane(myseg, j);
                    const float y = __int_as_float(
                        __builtin_amdgcn_readlane(__float_as_int(myy), j));
                    const vf4* fr = f4 + (size_t)j * 128;
                    const vf4* wr = (const vf4*)(wp + (size_t)c * 512);
                    vf4 a0 = __builtin_nontemporal_load(fr + lane);
                    vf4 a1 = __builtin_nontemporal_load(fr + lane + 64);
                    vf4 u0 = wr[lane];
                    vf4 u1 = wr[lane + 64];
                    acc_a -= y * dot8(a0, a1, u0, u1);
                }
            }
        }
    }

    // ---- Reduce: shuffle within wave, LDS across waves, one store per block.
    float acc = acc_a + acc_b;
    for (int off = 32; off > 0; off >>= 1)
        acc += __shfl_down(acc, off, 64);

    __shared__ float sacc[BLOCK / 64];
    const int lane = threadIdx.x & 63;
    const int wid  = threadIdx.x >> 6;
    if (lane == 0) sacc[wid] = acc;
    __syncthreads();

    if (threadIdx.x == 0) {
        float b = sacc[0] + sacc[1] + sacc[2] + sacc[3];
        if (blockout) blockout[blockIdx.x] = b;
        else          atomicAdd(out, b);
    }
}

extern "C" void kernel_launch(void* const* d_in, const int* in_sizes, int n_in,
                              void* d_out, int out_size, void* d_ws, size_t ws_size,
                              hipStream_t stream) {
    const float* wp    = (const float*)d_in[0];
    const float* wst   = (const float*)d_in[1];
    const float* feats = (const float*)d_in[2];
    const float* ys    = (const float*)d_in[3];
    const int*   seg   = (const int*)d_in[4];
    float* out = (float*)d_out;

    const int N = in_sizes[3];   // 200000 samples

    if (ws_size >= GRID * sizeof(float)) {
        float* part = (float*)d_ws;
        mrn_loss_kernel<<<GRID, BLOCK, 0, stream>>>(wp, wst, feats, ys, seg,
                                                    part, nullptr, N);
        final_reduce<<<1, 256, 0, stream>>>(part, out, (float)N);
    } else {
        // Fallback: init then atomics (should not trigger; ws is ample).
        init_out<<<1, 1, 0, stream>>>(out, (float)N);
        mrn_loss_kernel<<<GRID, BLOCK, 0, stream>>>(wp, wst, feats, ys, seg,
                                                    nullptr, out, N);
    }
}